// Round 10
// baseline (261.505 us; speedup 1.0000x reference)
//
#include <hip/hip_runtime.h>

#define NB 4
#define NN 256
#define NH 128
#define LN_EPS 1e-5f

__device__ __forceinline__ float elu1(float x){
  return x > 0.f ? x : (__expf(x) - 1.f);
}

// K0a: lin_in[b,i,:] = v@W_in.T + b_in ; lin_out[b,i,:] = v@W_out.T + b_out (fp32 exact)
__global__ __launch_bounds__(128) void lin_vw_kernel(
    const float* __restrict__ v,
    const float* __restrict__ W_in, const float* __restrict__ b_in,
    const float* __restrict__ W_out, const float* __restrict__ b_out,
    float* __restrict__ lin_in, float* __restrict__ lin_out)
{
  const int row = blockIdx.x;    // b*NN + i
  const int t = threadIdx.x;     // output col
  __shared__ float vs[NH];
  vs[t] = v[(size_t)row*NH + t];
  __syncthreads();
  const float4* wi = (const float4*)(W_in + t*NH);
  const float4* wo = (const float4*)(W_out + t*NH);
  const float4* vv = (const float4*)vs;
  float ai = b_in[t], ao = b_out[t];
  #pragma unroll
  for (int k = 0; k < NH/4; ++k){
    float4 x = vv[k];
    float4 a = wi[k], bq = wo[k];
    ai += x.x*a.x + x.y*a.y + x.z*a.z + x.w*a.w;
    ao += x.x*bq.x + x.y*bq.y + x.z*bq.z + x.w*bq.w;
  }
  lin_in[(size_t)row*NH + t]  = ai;
  lin_out[(size_t)row*NH + t] = ao;
}

// K0b: Wt_g[k][c] = W_e2e[c][k]  (64 KB, one-time)
__global__ __launch_bounds__(128) void transpose_w_kernel(
    const float* __restrict__ W, float* __restrict__ Wt)
{
  const int c = blockIdx.x;      // 0..127 (W row)
  const int k = threadIdx.x;     // 0..127
  Wt[(size_t)k*NH + c] = W[(size_t)c*NH + k];
}

// Main: one block per (b,j). No W LDS — Wt_g read coalesced from L1/L2.
// Thread (it,ic) owns 8 rows x 4 cols. Fused epilogue: LN->ELU->mask->store
// + register agg -> LN -> ELU -> out_v.  LDS: 2KB agg scratch only.
__global__ __launch_bounds__(256, 4) void nri_fused_tiled_kernel(
    const float* __restrict__ e,
    const float* __restrict__ v,
    const int* __restrict__ v_mask,
    const int* __restrict__ e_mask,
    const float* __restrict__ Wt_g,  const float* __restrict__ b_e2e,
    const float* __restrict__ g_e,   const float* __restrict__ be_e,
    const float* __restrict__ g_v,   const float* __restrict__ be_v,
    const float* __restrict__ lin_in, const float* __restrict__ lin_out,
    float* __restrict__ out_e, float* __restrict__ out_v)
{
  const int blk = blockIdx.x, b = blk >> 8, j = blk & (NN-1);
  const int tid = threadIdx.x;
  const int it  = tid >> 5;      // 0..7 : row group
  const int ic  = tid & 31;      // cols 4ic .. 4ic+3
  const int c0  = 4*ic;
  const int wave = tid >> 6;

  __shared__ float aggl[4][NH];  // per-wave agg partials (2 KB)
  __shared__ float red[4];

  // per-thread column constants
  float bj[4], gc[4], bec[4];
  {
    const float* lo = lin_out + (size_t)(b*NN + j)*NH + c0;
    #pragma unroll
    for (int cc = 0; cc < 4; ++cc){
      bj[cc]  = lo[cc] + b_e2e[c0+cc];
      gc[cc]  = g_e[c0+cc];
      bec[cc] = be_e[c0+cc];
    }
  }

  float aggacc[4] = {0.f, 0.f, 0.f, 0.f};

  const size_t ebase   = ((size_t)b*NN)*NN*NH + (size_t)j*NH;
  const size_t estride = (size_t)NN*NH;
  const int*   emcol   = e_mask + (size_t)(b*NN)*NN + j;

  for (int i0 = 0; i0 < NN; i0 += 64){
    const int ibase = i0 + it*8;

    const float* ep[8];
    #pragma unroll
    for (int rr = 0; rr < 8; ++rr)
      ep[rr] = e + ebase + (size_t)(ibase + rr)*estride;

    float acc[8][4];
    #pragma unroll
    for (int rr = 0; rr < 8; ++rr)
      #pragma unroll
      for (int cc = 0; cc < 4; ++cc) acc[rr][cc] = 0.f;

    for (int k = 0; k < NH; k += 4){
      // W: coalesced 512B wave-loads, L1/L2-resident (64 KB total)
      const float4 w0 = *(const float4*)(Wt_g + (size_t)(k+0)*NH + c0);
      const float4 w1 = *(const float4*)(Wt_g + (size_t)(k+1)*NH + c0);
      const float4 w2 = *(const float4*)(Wt_g + (size_t)(k+2)*NH + c0);
      const float4 w3 = *(const float4*)(Wt_g + (size_t)(k+3)*NH + c0);
      #pragma unroll
      for (int rr = 0; rr < 8; ++rr){
        const float4 ev = *(const float4*)(ep[rr] + k);  // 32-lane broadcast
        acc[rr][0] += ev.x*w0.x + ev.y*w1.x + ev.z*w2.x + ev.w*w3.x;
        acc[rr][1] += ev.x*w0.y + ev.y*w1.y + ev.z*w2.y + ev.w*w3.y;
        acc[rr][2] += ev.x*w0.z + ev.y*w1.z + ev.z*w2.z + ev.w*w3.z;
        acc[rr][3] += ev.x*w0.w + ev.y*w1.w + ev.z*w2.w + ev.w*w3.w;
      }
    }

    // epilogue: +lin_in +bias -> LN -> ELU -> mask -> store + agg
    #pragma unroll
    for (int rr = 0; rr < 8; ++rr){
      const int i = ibase + rr;
      const float4 li = *(const float4*)(lin_in + (size_t)(b*NN + i)*NH + c0);
      float x0 = acc[rr][0] + li.x + bj[0];
      float x1 = acc[rr][1] + li.y + bj[1];
      float x2 = acc[rr][2] + li.z + bj[2];
      float x3 = acc[rr][3] + li.w + bj[3];

      // LN over 128 = 4 in-thread x 32 same-it lanes (shfl_xor m<=16 stays in half)
      float s  = x0 + x1 + x2 + x3;
      float s2 = x0*x0 + x1*x1 + x2*x2 + x3*x3;
      #pragma unroll
      for (int m = 1; m <= 16; m <<= 1){
        s  += __shfl_xor(s,  m, 64);
        s2 += __shfl_xor(s2, m, 64);
      }
      const float mu  = s * (1.f/NH);
      const float var = s2 * (1.f/NH) - mu*mu;
      const float rs  = rsqrtf(var + LN_EPS);

      const int zf = (i == j) || emcol[(size_t)i*NN];
      float4 hh;
      hh.x = zf ? 0.f : elu1((x0 - mu)*rs*gc[0] + bec[0]);
      hh.y = zf ? 0.f : elu1((x1 - mu)*rs*gc[1] + bec[1]);
      hh.z = zf ? 0.f : elu1((x2 - mu)*rs*gc[2] + bec[2]);
      hh.w = zf ? 0.f : elu1((x3 - mu)*rs*gc[3] + bec[3]);
      *(float4*)(out_e + ebase + (size_t)i*estride + c0) = hh;
      aggacc[0] += hh.x; aggacc[1] += hh.y;
      aggacc[2] += hh.z; aggacc[3] += hh.w;
    }
  }

  // ---- fused out_v: reduce aggacc across it-groups, then waves ----
  #pragma unroll
  for (int cc = 0; cc < 4; ++cc)
    aggacc[cc] += __shfl_xor(aggacc[cc], 32, 64);   // combine it pair within wave
  if ((tid & 63) < 32){
    #pragma unroll
    for (int cc = 0; cc < 4; ++cc) aggl[wave][c0+cc] = aggacc[cc];
  }
  __syncthreads();

  float a = 0.f, s = 0.f, s2 = 0.f;
  if (tid < NH){
    const int c = tid;
    a = aggl[0][c] + aggl[1][c] + aggl[2][c] + aggl[3][c];
    s = a; s2 = a*a;
    #pragma unroll
    for (int m = 1; m <= 32; m <<= 1){
      s  += __shfl_xor(s,  m, 64);
      s2 += __shfl_xor(s2, m, 64);
    }
  }
  if (tid < NH && (tid & 63) == 0){
    red[(tid>>6)*2] = s; red[(tid>>6)*2 + 1] = s2;
  }
  __syncthreads();
  if (tid < NH){
    const int c = tid;
    const float S  = red[0] + red[2];
    const float S2 = red[1] + red[3];
    const float mu  = S * (1.f/NH);
    const float var = S2 * (1.f/NH) - mu*mu;
    const float rs  = rsqrtf(var + LN_EPS);
    const float h   = elu1((a - mu)*rs*g_v[c] + be_v[c]);
    const int vm = v_mask[b*NN + j];
    const float vv = vm ? 0.f : v[(size_t)(b*NN + j)*NH + c];
    out_v[(size_t)(b*NN + j)*NH + c] = vv + h;
  }
}

extern "C" void kernel_launch(void* const* d_in, const int* in_sizes, int n_in,
                              void* d_out, int out_size, void* d_ws, size_t ws_size,
                              hipStream_t stream)
{
  const float* v      = (const float*)d_in[0];
  const float* e      = (const float*)d_in[1];
  const int*   v_mask = (const int*)d_in[2];
  const int*   e_mask = (const int*)d_in[3];
  const float* W_in   = (const float*)d_in[4];
  const float* b_in   = (const float*)d_in[5];
  const float* W_out  = (const float*)d_in[6];
  const float* b_out  = (const float*)d_in[7];
  const float* W_e2e  = (const float*)d_in[8];
  const float* b_e2e  = (const float*)d_in[9];
  const float* g_e    = (const float*)d_in[10];
  const float* be_e   = (const float*)d_in[11];
  const float* g_v    = (const float*)d_in[12];
  const float* be_v   = (const float*)d_in[13];

  float* lin_in  = (float*)d_ws;                 // [NB*NN, NH]
  float* lin_out = lin_in + NB*NN*NH;            // [NB*NN, NH]
  float* Wt_g    = lin_out + NB*NN*NH;           // [NH, NH] transposed W_e2e
  float* out_v = (float*)d_out;                  // [NB,NN,NH]
  float* out_e = out_v + (size_t)NB*NN*NH;       // [NB,NN,NN,NH]

  lin_vw_kernel<<<NB*NN, NH, 0, stream>>>(v, W_in, b_in, W_out, b_out,
                                          lin_in, lin_out);
  transpose_w_kernel<<<NH, NH, 0, stream>>>(W_e2e, Wt_g);
  nri_fused_tiled_kernel<<<NB*NN, 256, 0, stream>>>(e, v, v_mask, e_mask,
                                                    Wt_g, b_e2e, g_e, be_e,
                                                    g_v, be_v,
                                                    lin_in, lin_out,
                                                    out_e, out_v);
}